// Round 1
// baseline (6498.640 us; speedup 1.0000x reference)
//
#include <hip/hip_runtime.h>
#include <math.h>

// ---------------- problem constants ----------------
#define Bq 2
#define Sq 1024
#define Dq 1024
#define Lq 2
#define HDq 64
#define Hq 16
#define KVq 4
#define Fq 2048
#define Eq 8
#define TOPK 2
#define Vq 32000
#define Nq (Bq*Sq)          // 2048 tokens
#define REPq (Hq/KVq)       // 4
#define EPSq 1e-5f

// ---------------- workspace layout (float offsets) ----------------
// total ~42M floats (~168 MB) + small int area
#define O_H   ((size_t)0)                       // 2M  hidden state (N x D)
#define O_X   ((size_t)2*1024*1024)             // 2M  normed activations
#define O_Q   ((size_t)4*1024*1024)             // 2M  q (N x H*HD)
#define O_K   ((size_t)6*1024*1024)             // 512K k (N x KV*HD)
#define O_V   (O_K + (size_t)512*1024)          // 512K v
#define O_ATT ((size_t)7*1024*1024)             // 2M  attention output (N x D)
#define O_COS ((size_t)9*1024*1024)             // 32K rope cos table (S x 32)
#define O_SIN (O_COS + 32768)                   // 32K rope sin
#define O_LOG (O_SIN + 32768)                   // 16K gate logits (N x E)
#define O_TPW (O_LOG + 16384)                   // 4K  top-k weights (N x 2)
#define O_SC  ((size_t)10*1024*1024)            // 32M scores (B*H*S*S) -- reused by MoE:
#define O_XG  (O_SC)                            // 4M  gathered tokens (4096 x D)
#define O_H13 (O_SC + (size_t)4*1024*1024)      // 8M  h1 then silu(h1)*h3 (4096 x F)
#define O_H3  (O_SC + (size_t)12*1024*1024)     // 8M  h3
#define O_Y   (O_SC + (size_t)20*1024*1024)     // 4M  expert outputs (4096 x D)
#define O_INT ((size_t)42*1024*1024)            // int area

// ---------------- small kernels ----------------

__global__ void k_rope_table(const int* __restrict__ pos, float* __restrict__ cosT,
                             float* __restrict__ sinT) {
  int i = blockIdx.x * blockDim.x + threadIdx.x;   // 0 .. S*32-1
  if (i >= Sq * 32) return;
  int s = i >> 5, f = i & 31;
  float freq = 1.0f / powf(1.0e6f, (float)f / 32.0f);
  float ang = (float)pos[s] * freq;
  cosT[i] = cosf(ang);
  sinT[i] = sinf(ang);
}

__global__ void k_embed(const int* __restrict__ ids, const float* __restrict__ emb,
                        float* __restrict__ h) {
  int n = blockIdx.x;
  const float4* src = (const float4*)(emb + (size_t)ids[n] * Dq);
  float4* dst = (float4*)(h + (size_t)n * Dq);
  dst[threadIdx.x] = src[threadIdx.x];   // 256 threads x 4 floats = 1024
}

__global__ void k_rmsnorm(const float* __restrict__ in, const float* __restrict__ w,
                          float* __restrict__ out) {
  int n = blockIdx.x;
  int t = threadIdx.x;
  float4 v = ((const float4*)(in + (size_t)n * Dq))[t];
  float ss = v.x*v.x + v.y*v.y + v.z*v.z + v.w*v.w;
  #pragma unroll
  for (int o = 32; o > 0; o >>= 1) ss += __shfl_down(ss, o);
  __shared__ float red[4];
  if ((t & 63) == 0) red[t >> 6] = ss;
  __syncthreads();
  float tot = red[0] + red[1] + red[2] + red[3];
  float r = rsqrtf(tot / (float)Dq + EPSq);
  float4 wl = ((const float4*)w)[t];
  float4 o4;
  o4.x = v.x * r * wl.x; o4.y = v.y * r * wl.y;
  o4.z = v.z * r * wl.z; o4.w = v.w * r * wl.w;
  ((float4*)(out + (size_t)n * Dq))[t] = o4;
}

// apply rope in place; heads = H (q) or KV (k); total = N*heads*32 pairs
__global__ void k_rope(float* __restrict__ xp, const float* __restrict__ cosT,
                       const float* __restrict__ sinT, int heads, int total) {
  int i = blockIdx.x * blockDim.x + threadIdx.x;
  if (i >= total) return;
  int np = heads * 32;
  int n = i / np, r = i % np;
  int hh = r >> 5, f = r & 31;
  int s = n & (Sq - 1);
  float c = cosT[s * 32 + f], sn = sinT[s * 32 + f];
  float* pp = xp + ((size_t)n * heads + hh) * HDq + 2 * f;
  float xe = pp[0], xo = pp[1];
  pp[0] = xe * c - xo * sn;
  pp[1] = xe * sn + xo * c;
}

// ---------------- generic f32 GEMM: C[=|+=] A @ B ----------------
// mode 0: batched via linear strides (sA,sB,sC)
// mode 1: grouped MoE: z=expert, rows base/cnt from grpBase/grpCnt, B += z*sB
// mode 2: attention PV: z = b*H+h; A=scores, B=v (strided heads), C=att
#define BMt 128
#define BNt 128
#define BKt 8
__global__ __launch_bounds__(256)
void k_gemm(const float* __restrict__ A, const float* __restrict__ B,
            float* __restrict__ C,
            int N, int Kd,
            long long sA, long long sB, long long sC,
            int lda, int ldb, int ldc,
            int addC, int mode,
            const int* __restrict__ grpBase, const int* __restrict__ grpCnt,
            int M) {
  __shared__ float As[BKt][BMt];
  __shared__ float Bs[BKt][BNt];
  int z = blockIdx.z;
  const float* Ab; const float* Bb; float* Cb;
  int Me = M;
  if (mode == 1) {
    int base = grpBase[z];
    Me = grpCnt[z];
    Ab = A + (long long)base * lda;
    Cb = C + (long long)base * ldc;
    Bb = B + (long long)z * sB;
  } else if (mode == 2) {
    int b = z / Hq, hh = z % Hq;
    Ab = A + (long long)z * sA;
    Bb = B + (long long)b * (Sq * KVq * HDq) + (hh / REPq) * HDq;
    Cb = C + (long long)b * (Sq * Hq * HDq) + hh * HDq;
  } else {
    Ab = A + (long long)z * sA;
    Bb = B + (long long)z * sB;
    Cb = C + (long long)z * sC;
  }
  int m0 = blockIdx.y * BMt;
  int n0 = blockIdx.x * BNt;
  if (m0 >= Me) return;
  int t = threadIdx.x;
  int tx = t & 15, ty = t >> 4;
  int ar = t >> 1, ac = (t & 1) * 4;     // A tile: 128 rows x 8 cols
  int br = t >> 5, bc = (t & 31) * 4;    // B tile: 8 rows x 128 cols
  float acc[8][8];
  #pragma unroll
  for (int i = 0; i < 8; i++)
    #pragma unroll
    for (int j = 0; j < 8; j++) acc[i][j] = 0.0f;
  int nk = Kd / BKt;
  for (int kt = 0; kt < nk; ++kt) {
    int k0 = kt * BKt;
    float4 av = make_float4(0.f, 0.f, 0.f, 0.f);
    if (m0 + ar < Me) av = *(const float4*)(Ab + (long long)(m0 + ar) * lda + k0 + ac);
    As[ac + 0][ar] = av.x; As[ac + 1][ar] = av.y;
    As[ac + 2][ar] = av.z; As[ac + 3][ar] = av.w;
    float4 bv = make_float4(0.f, 0.f, 0.f, 0.f);
    if (n0 + bc < N) bv = *(const float4*)(Bb + (long long)(k0 + br) * ldb + n0 + bc);
    *(float4*)&Bs[br][bc] = bv;
    __syncthreads();
    #pragma unroll
    for (int kk = 0; kk < BKt; ++kk) {
      float a[8], b[8];
      *(float4*)&a[0] = *(const float4*)&As[kk][ty * 8];
      *(float4*)&a[4] = *(const float4*)&As[kk][ty * 8 + 4];
      *(float4*)&b[0] = *(const float4*)&Bs[kk][tx * 8];
      *(float4*)&b[4] = *(const float4*)&Bs[kk][tx * 8 + 4];
      #pragma unroll
      for (int i = 0; i < 8; i++)
        #pragma unroll
        for (int j = 0; j < 8; j++) acc[i][j] += a[i] * b[j];
    }
    __syncthreads();
  }
  #pragma unroll
  for (int i = 0; i < 8; i++) {
    int gr = m0 + ty * 8 + i;
    if (gr < Me) {
      #pragma unroll
      for (int j4 = 0; j4 < 8; j4 += 4) {
        int gc = n0 + tx * 8 + j4;
        if (gc < N) {
          float* cp = Cb + (long long)gr * ldc + gc;
          float4 o;
          o.x = acc[i][j4 + 0]; o.y = acc[i][j4 + 1];
          o.z = acc[i][j4 + 2]; o.w = acc[i][j4 + 3];
          if (addC) {
            float4 p = *(const float4*)cp;
            o.x += p.x; o.y += p.y; o.z += p.z; o.w += p.w;
          }
          *(float4*)cp = o;
        }
      }
    }
  }
}

// ---------------- attention: scores = scale * Q K^T (per b,h 64x64 tiles) -------
__global__ __launch_bounds__(256)
void k_scores(const float* __restrict__ q, const float* __restrict__ kb,
              float* __restrict__ sc) {
  int z = blockIdx.z;
  int b = z >> 4, hh = z & 15;
  int q0 = blockIdx.y * 64, k0 = blockIdx.x * 64;
  if (k0 > q0 + 63) return;   // fully masked tile: softmax never reads it
  __shared__ float Qs[64][68];
  __shared__ float Ks[64][68];
  int t = threadIdx.x;
  const float* qbase = q + ((long long)(b * Sq) * Hq + hh) * HDq;
  const float* kbase = kb + ((long long)(b * Sq) * KVq + (hh >> 2)) * HDq;
  #pragma unroll
  for (int j = 0; j < 4; j++) {
    int l = t + j * 256;
    int r = l >> 4, c = (l & 15) * 4;
    float4 v = *(const float4*)(qbase + (long long)(q0 + r) * (Hq * HDq) + c);
    Qs[r][c] = v.x; Qs[r][c + 1] = v.y; Qs[r][c + 2] = v.z; Qs[r][c + 3] = v.w;
    float4 w = *(const float4*)(kbase + (long long)(k0 + r) * (KVq * HDq) + c);
    Ks[r][c] = w.x; Ks[r][c + 1] = w.y; Ks[r][c + 2] = w.z; Ks[r][c + 3] = w.w;
  }
  __syncthreads();
  int tx = t & 15, ty = t >> 4;
  float acc[4][4];
  #pragma unroll
  for (int i = 0; i < 4; i++)
    #pragma unroll
    for (int j = 0; j < 4; j++) acc[i][j] = 0.0f;
  for (int d = 0; d < 64; d++) {
    float a[4], b2[4];
    #pragma unroll
    for (int i = 0; i < 4; i++) a[i] = Qs[ty * 4 + i][d];
    #pragma unroll
    for (int j = 0; j < 4; j++) b2[j] = Ks[tx * 4 + j][d];
    #pragma unroll
    for (int i = 0; i < 4; i++)
      #pragma unroll
      for (int j = 0; j < 4; j++) acc[i][j] += a[i] * b2[j];
  }
  const float scale = 0.125f;  // HD^-0.5
  #pragma unroll
  for (int i = 0; i < 4; i++) {
    float* out = sc + ((long long)z * Sq + (q0 + ty * 4 + i)) * Sq + k0 + tx * 4;
    float4 o;
    o.x = acc[i][0] * scale; o.y = acc[i][1] * scale;
    o.z = acc[i][2] * scale; o.w = acc[i][3] * scale;
    *(float4*)out = o;
  }
}

// causal softmax per row; one wave per row (4 rows / block)
__global__ __launch_bounds__(256)
void k_softmax(float* __restrict__ sc) {
  int row = blockIdx.x * 4 + (threadIdx.x >> 6);
  int lane = threadIdx.x & 63;
  int qi = row & (Sq - 1);
  float* p = sc + (long long)row * Sq;
  float vals[16];
  float mx = -3.0e38f;
  #pragma unroll
  for (int j = 0; j < 16; j++) {
    int idx = lane + j * 64;
    float v = (idx <= qi) ? p[idx] : -3.0e38f;
    vals[j] = v;
    mx = fmaxf(mx, v);
  }
  #pragma unroll
  for (int o = 32; o > 0; o >>= 1) mx = fmaxf(mx, __shfl_xor(mx, o));
  float sum = 0.0f;
  #pragma unroll
  for (int j = 0; j < 16; j++) {
    int idx = lane + j * 64;
    float e = (idx <= qi) ? expf(vals[j] - mx) : 0.0f;
    vals[j] = e;
    sum += e;
  }
  #pragma unroll
  for (int o = 32; o > 0; o >>= 1) sum += __shfl_xor(sum, o);
  float inv = 1.0f / sum;
  #pragma unroll
  for (int j = 0; j < 16; j++) p[lane + j * 64] = vals[j] * inv;
}

// ---------------- MoE routing ----------------
__global__ void k_gate(const float* __restrict__ x, const float* __restrict__ gw,
                       float* __restrict__ logits) {
  int n = blockIdx.x * 4 + (threadIdx.x >> 6);
  int lane = threadIdx.x & 63;
  float acc[Eq];
  #pragma unroll
  for (int e = 0; e < Eq; e++) acc[e] = 0.0f;
  for (int d = lane; d < Dq; d += 64) {
    float xv = x[(size_t)n * Dq + d];
    const float* g = gw + (size_t)d * Eq;
    #pragma unroll
    for (int e = 0; e < Eq; e++) acc[e] += xv * g[e];
  }
  #pragma unroll
  for (int o = 32; o > 0; o >>= 1)
    #pragma unroll
    for (int e = 0; e < Eq; e++) acc[e] += __shfl_xor(acc[e], o);
  if (lane == 0) {
    #pragma unroll
    for (int e = 0; e < Eq; e++) logits[(size_t)n * Eq + e] = acc[e];
  }
}

__global__ void k_zero_counts(int* c) { if (threadIdx.x < 16) c[threadIdx.x] = 0; }

__global__ void k_route_count(const float* __restrict__ logits, float* __restrict__ topw,
                              int* __restrict__ sel, int* __restrict__ counts) {
  int n = blockIdx.x * blockDim.x + threadIdx.x;
  if (n >= Nq) return;
  const float* lg = logits + (size_t)n * Eq;
  int i1 = 0; float v1 = lg[0];
  #pragma unroll
  for (int e = 1; e < Eq; e++) if (lg[e] > v1) { v1 = lg[e]; i1 = e; }
  int i2 = -1; float v2 = -3.0e38f;
  #pragma unroll
  for (int e = 0; e < Eq; e++) if (e != i1 && lg[e] > v2) { v2 = lg[e]; i2 = e; }
  float e2 = expf(v2 - v1);
  float s = 1.0f + e2;
  topw[n * 2 + 0] = 1.0f / s;
  topw[n * 2 + 1] = e2 / s;
  sel[n * 2 + 0] = i1;
  sel[n * 2 + 1] = i2;
  atomicAdd(&counts[i1], 1);
  atomicAdd(&counts[i2], 1);
}

__global__ void k_scan(const int* __restrict__ counts, int* __restrict__ bases,
                       int* __restrict__ counts2) {
  if (threadIdx.x == 0) {
    int s = 0;
    for (int e = 0; e < Eq; e++) { bases[e] = s; s += counts[e]; counts2[e] = 0; }
  }
}

__global__ void k_route_assign(const int* __restrict__ sel, int* __restrict__ counts2,
                               const int* __restrict__ bases, int* __restrict__ row2tok,
                               int* __restrict__ posof) {
  int n = blockIdx.x * blockDim.x + threadIdx.x;
  if (n >= Nq) return;
  #pragma unroll
  for (int slot = 0; slot < TOPK; slot++) {
    int e = sel[n * 2 + slot];
    int pos = atomicAdd(&counts2[e], 1);
    int row = bases[e] + pos;
    row2tok[row] = n;
    posof[n * 2 + slot] = row;
  }
}

__global__ void k_gather(const float* __restrict__ x, const int* __restrict__ row2tok,
                         float* __restrict__ xg) {
  int row = blockIdx.x;
  int tok = row2tok[row];
  const float4* src = (const float4*)(x + (size_t)tok * Dq);
  float4* dst = (float4*)(xg + (size_t)row * Dq);
  dst[threadIdx.x] = src[threadIdx.x];
}

__global__ void k_silumul(float* __restrict__ h13, const float* __restrict__ h3) {
  int i = blockIdx.x * blockDim.x + threadIdx.x;   // float4 index
  float4 a = ((const float4*)h13)[i];
  float4 b = ((const float4*)h3)[i];
  float4 o;
  o.x = (a.x / (1.0f + expf(-a.x))) * b.x;
  o.y = (a.y / (1.0f + expf(-a.y))) * b.y;
  o.z = (a.z / (1.0f + expf(-a.z))) * b.z;
  o.w = (a.w / (1.0f + expf(-a.w))) * b.w;
  ((float4*)h13)[i] = o;
}

__global__ void k_moe_combine(float* __restrict__ h, const float* __restrict__ y,
                              const float* __restrict__ topw, const int* __restrict__ posof) {
  int n = blockIdx.x;
  int t = threadIdx.x;
  float w0 = topw[n * 2 + 0], w1 = topw[n * 2 + 1];
  int r0 = posof[n * 2 + 0], r1 = posof[n * 2 + 1];
  float4 a = ((const float4*)(y + (size_t)r0 * Dq))[t];
  float4 b = ((const float4*)(y + (size_t)r1 * Dq))[t];
  float4 hv = ((float4*)(h + (size_t)n * Dq))[t];
  hv.x += w0 * a.x + w1 * b.x;
  hv.y += w0 * a.y + w1 * b.y;
  hv.z += w0 * a.z + w1 * b.z;
  hv.w += w0 * a.w + w1 * b.w;
  ((float4*)(h + (size_t)n * Dq))[t] = hv;
}

// ---------------- launch ----------------
extern "C" void kernel_launch(void* const* d_in, const int* in_sizes, int n_in,
                              void* d_out, int out_size, void* d_ws, size_t ws_size,
                              hipStream_t stream) {
  const int* ids       = (const int*)d_in[0];
  const int* pos       = (const int*)d_in[1];
  const float* tok_emb = (const float*)d_in[2];
  const float* attn_nw = (const float*)d_in[3];
  const float* ffn_nw  = (const float*)d_in[4];
  const float* wq      = (const float*)d_in[5];
  const float* wk      = (const float*)d_in[6];
  const float* wv      = (const float*)d_in[7];
  const float* wo      = (const float*)d_in[8];
  const float* gate    = (const float*)d_in[9];
  const float* w1      = (const float*)d_in[10];
  const float* w2      = (const float*)d_in[11];
  const float* w3      = (const float*)d_in[12];
  const float* fnw     = (const float*)d_in[13];
  const float* outw    = (const float*)d_in[14];
  float* out = (float*)d_out;
  float* ws = (float*)d_ws;

  float* h    = ws + O_H;
  float* x    = ws + O_X;
  float* q    = ws + O_Q;
  float* kb   = ws + O_K;
  float* vb   = ws + O_V;
  float* att  = ws + O_ATT;
  float* cosT = ws + O_COS;
  float* sinT = ws + O_SIN;
  float* logits = ws + O_LOG;
  float* topw = ws + O_TPW;
  float* sc   = ws + O_SC;
  float* xg   = ws + O_XG;
  float* h13  = ws + O_H13;
  float* h3   = ws + O_H3;
  float* y    = ws + O_Y;
  int* ip = (int*)(ws + O_INT);
  int* counts = ip;
  int* counts2 = ip + 8;
  int* bases = ip + 16;
  int* sel = ip + 32;
  int* row2tok = ip + 32 + 4096;
  int* posof = ip + 32 + 8192;

  auto gemm = [&](const float* A, const float* Bm, float* Cm,
                  int M, int N, int Kd,
                  long long sA, long long sB, long long sC,
                  int lda, int ldb, int ldc, int addC, int mode,
                  const int* gb, const int* gcnt, int nz, int Mgrid) {
    dim3 g((N + BNt - 1) / BNt, (Mgrid + BMt - 1) / BMt, nz);
    k_gemm<<<g, 256, 0, stream>>>(A, Bm, Cm, N, Kd, sA, sB, sC, lda, ldb, ldc,
                                  addC, mode, gb, gcnt, M);
  };

  k_rope_table<<<128, 256, 0, stream>>>(pos, cosT, sinT);
  k_embed<<<Nq, 256, 0, stream>>>(ids, tok_emb, h);

  for (int l = 0; l < Lq; l++) {
    // ---- attention ----
    k_rmsnorm<<<Nq, 256, 0, stream>>>(h, attn_nw + (size_t)l * Dq, x);
    gemm(x, wq + (long long)l * Dq * Hq * HDq, q, Nq, Hq * HDq, Dq,
         0, 0, 0, Dq, Hq * HDq, Hq * HDq, 0, 0, nullptr, nullptr, 1, Nq);
    gemm(x, wk + (long long)l * Dq * KVq * HDq, kb, Nq, KVq * HDq, Dq,
         0, 0, 0, Dq, KVq * HDq, KVq * HDq, 0, 0, nullptr, nullptr, 1, Nq);
    gemm(x, wv + (long long)l * Dq * KVq * HDq, vb, Nq, KVq * HDq, Dq,
         0, 0, 0, Dq, KVq * HDq, KVq * HDq, 0, 0, nullptr, nullptr, 1, Nq);
    k_rope<<<(Nq * Hq * 32) / 256, 256, 0, stream>>>(q, cosT, sinT, Hq, Nq * Hq * 32);
    k_rope<<<(Nq * KVq * 32) / 256, 256, 0, stream>>>(kb, cosT, sinT, KVq, Nq * KVq * 32);
    k_scores<<<dim3(Sq / 64, Sq / 64, Bq * Hq), 256, 0, stream>>>(q, kb, sc);
    k_softmax<<<(Bq * Hq * Sq) / 4, 256, 0, stream>>>(sc);
    gemm(sc, vb, att, Sq, HDq, Sq,
         (long long)Sq * Sq, 0, 0, Sq, KVq * HDq, Hq * HDq, 0, 2,
         nullptr, nullptr, Bq * Hq, Sq);
    gemm(att, wo + (long long)l * Hq * HDq * Dq, h, Nq, Dq, Hq * HDq,
         0, 0, 0, Hq * HDq, Dq, Dq, 1, 0, nullptr, nullptr, 1, Nq);   // h += att @ wo

    // ---- MoE ----
    k_rmsnorm<<<Nq, 256, 0, stream>>>(h, ffn_nw + (size_t)l * Dq, x);
    k_gate<<<Nq / 4, 256, 0, stream>>>(x, gate + (size_t)l * Dq * Eq, logits);
    k_zero_counts<<<1, 32, 0, stream>>>(counts);
    k_route_count<<<Nq / 256, 256, 0, stream>>>(logits, topw, sel, counts);
    k_scan<<<1, 1, 0, stream>>>(counts, bases, counts2);
    k_route_assign<<<Nq / 256, 256, 0, stream>>>(sel, counts2, bases, row2tok, posof);
    k_gather<<<Nq * TOPK, 256, 0, stream>>>(x, row2tok, xg);
    gemm(xg, w1 + (long long)l * Eq * Dq * Fq, h13, 0, Fq, Dq,
         0, (long long)Dq * Fq, 0, Dq, Fq, Fq, 0, 1, bases, counts, Eq, Nq);
    gemm(xg, w3 + (long long)l * Eq * Dq * Fq, h3, 0, Fq, Dq,
         0, (long long)Dq * Fq, 0, Dq, Fq, Fq, 0, 1, bases, counts, Eq, Nq);
    k_silumul<<<(Nq * TOPK * Fq / 4) / 256, 256, 0, stream>>>(h13, h3);
    gemm(h13, w2 + (long long)l * Eq * Fq * Dq, y, 0, Dq, Fq,
         0, (long long)Fq * Dq, 0, Fq, Dq, Dq, 0, 1, bases, counts, Eq, Nq);
    k_moe_combine<<<Nq, 256, 0, stream>>>(h, y, topw, posof);
  }

  // ---- final norm + LM head ----
  k_rmsnorm<<<Nq, 256, 0, stream>>>(h, fnw, x);
  gemm(x, outw, out, Nq, Vq, Dq, 0, 0, 0, Dq, Vq, Vq, 0, 0, nullptr, nullptr, 1, Nq);
}